// Round 14
// baseline (322.134 us; speedup 1.0000x reference)
//
#include <hip/hip_runtime.h>

// Problem constants: B=16, MAX_LEN=100, LOC_MAX=20000, EMB=256, D_DELTA=2
#define NB 16
#define MLEN 100
#define EMBD 256
#define LMAX 20000
#define NKC 4               // K chunks of 32 m's (100 zero-padded to 128 in B)
#define NWAVES (NB * (LMAX / 32))          // 10000 one-wave tiles: wid = lt*16 + b
#define PREP_TASKS (NB * NKC * 16 * 64)    // 65536: (b,kc,etg,lane)

typedef __attribute__((ext_vector_type(4))) float f32x4;
typedef __attribute__((ext_vector_type(2))) float f32x2;
typedef __attribute__((ext_vector_type(8))) short bf16x8;

__device__ __forceinline__ unsigned short f2bf(float x) {
    union { float f; unsigned u; } a; a.f = x;
    unsigned r = a.u + 0x7FFFu + ((a.u >> 16) & 1u);
    return (unsigned short)(r >> 16);
}
__device__ __forceinline__ float bf2f(unsigned short h) {
    union { unsigned u; float f; } a; a.u = ((unsigned)h) << 16;
    return a.f;
}
__device__ __forceinline__ bf16x8 u4bf(uint4 u) {
    union { uint4 a; bf16x8 b; } c; c.a = u; return c.b;
}

// ---------------- Kernel 1: pack vwA = vw[m]*attn[b][m][e] into MFMA B-fragments (hi/lo) ----------------
// frag f = (b*NKC+kc)*16 + etg ; lane: e = etg*16 + (lane&15), k = (lane>>4)*8 + j, m = kc*32 + k
// m >= MLEN  ->  exact zero (pairs with predicated-zero A loads in main kernel)
__global__ __launch_bounds__(256)
void prep2_kernel(const float* __restrict__ attn, const float* __restrict__ vw,
                  unsigned short* __restrict__ Bhi, unsigned short* __restrict__ Blo) {
    const int gid  = blockIdx.x * 256 + threadIdx.x;   // < 65536
    const int lane = gid & 63;
    const int f    = gid >> 6;
    const int etg  = f & 15;
    const int kcb  = f >> 4;
    const int kc   = kcb & 3;
    const int b    = kcb >> 2;
    const int e    = etg * 16 + (lane & 15);
    const int m0   = kc * 32 + (lane >> 4) * 8;
    unsigned h[8], l[8];
    #pragma unroll
    for (int j = 0; j < 8; ++j) {
        const int m = m0 + j;
        float x = 0.f;
        if (m < MLEN) x = vw[m] * attn[((size_t)b * MLEN + m) * EMBD + e];
        const unsigned short hh = f2bf(x);
        h[j] = hh;
        l[j] = f2bf(x - bf2f(hh));
    }
    uint4 hi = make_uint4(h[0]|(h[1]<<16), h[2]|(h[3]<<16), h[4]|(h[5]<<16), h[6]|(h[7]<<16));
    uint4 lo = make_uint4(l[0]|(l[1]<<16), l[2]|(l[3]<<16), l[4]|(l[5]<<16), l[6]|(l[7]<<16));
    reinterpret_cast<uint4*>(Bhi)[gid] = hi;
    reinterpret_cast<uint4*>(Blo)[gid] = lo;
}

// ---------------- Kernel 2: barrier-free, LDS-free fused GEMM + epilogue ----------------
// One wave owns (b, 32 l's): computes G[l,e] = sum_m dsum[m,l]*vwA[m,e] over ALL 256 e's
// (acc[2 sub][16 et]), then p[l] = sum_e G[l,e]*E[1+l,e] wave-privately. No LDS, no barriers.
// A-frag loads: lane element j  <-  sdelta[b][kc*32+lhi*8+j][l0+s*16+llo] (pair-summed, hi/lo split).
// Per load instr: 4 x 128B full cache lines. Every sdelta byte read exactly once.
__global__ __launch_bounds__(64)
void main_kernel(const unsigned short* __restrict__ Bhi, const unsigned short* __restrict__ Blo,
                 const float* __restrict__ sdelta, const float* __restrict__ embt,
                 float* __restrict__ out) {
    const int wid  = blockIdx.x;        // 0..9999, wid = lt*16 + b
    const int b    = wid & 15;
    const int lt   = wid >> 4;          // 0..624
    const int l0   = lt * 32;           // 20000 % 32 == 0 -> no l masking ever
    const int lane = threadIdx.x;       // 0..63
    const int llo  = lane & 15;
    const int lhi  = lane >> 4;

    f32x4 acc[2][16];
    #pragma unroll
    for (int s = 0; s < 2; ++s)
        #pragma unroll
        for (int et = 0; et < 16; ++et)
            acc[s][et] = (f32x4){0.f, 0.f, 0.f, 0.f};

    const float* sdb = sdelta + (size_t)b * MLEN * (LMAX * 2);
    const int c0 = (l0 + llo) * 2;          // byte-col (floats) for sub 0
    const int c1 = (l0 + 16 + llo) * 2;     // sub 1

    for (int kc = 0; kc < NKC; ++kc) {
        // ---- A: 16 predicated f32x2 loads -> pair-sum -> hi/lo bf16 fragments (registers only) ----
        f32x2 v0[8], v1[8];
        #pragma unroll
        for (int j = 0; j < 8; ++j) {
            const int m = kc * 32 + lhi * 8 + j;
            f32x2 a = {0.f, 0.f}, c = {0.f, 0.f};
            if (m < MLEN) {
                const float* rp = sdb + (size_t)m * (LMAX * 2);
                a = *reinterpret_cast<const f32x2*>(rp + c0);
                c = *reinterpret_cast<const f32x2*>(rp + c1);
            }
            v0[j] = a;
            v1[j] = c;
        }
        unsigned h0[8], L0[8], h1[8], L1[8];
        #pragma unroll
        for (int j = 0; j < 8; ++j) {
            const float s0 = v0[j][0] + v0[j][1];
            const float s1 = v1[j][0] + v1[j][1];
            const unsigned short a0 = f2bf(s0); h0[j] = a0; L0[j] = f2bf(s0 - bf2f(a0));
            const unsigned short a1 = f2bf(s1); h1[j] = a1; L1[j] = f2bf(s1 - bf2f(a1));
        }
        const bf16x8 ah0 = u4bf(make_uint4(h0[0]|(h0[1]<<16), h0[2]|(h0[3]<<16), h0[4]|(h0[5]<<16), h0[6]|(h0[7]<<16)));
        const bf16x8 al0 = u4bf(make_uint4(L0[0]|(L0[1]<<16), L0[2]|(L0[3]<<16), L0[4]|(L0[5]<<16), L0[6]|(L0[7]<<16)));
        const bf16x8 ah1 = u4bf(make_uint4(h1[0]|(h1[1]<<16), h1[2]|(h1[3]<<16), h1[4]|(h1[5]<<16), h1[6]|(h1[7]<<16)));
        const bf16x8 al1 = u4bf(make_uint4(L1[0]|(L1[1]<<16), L1[2]|(L1[3]<<16), L1[4]|(L1[5]<<16), L1[6]|(L1[7]<<16)));

        // ---- B/MFMA: 16 e-tiles; B pair from L2 (hot chip-wide), 6 MFMAs each ----
        #pragma unroll
        for (int et = 0; et < 16; ++et) {
            const size_t bo = (((size_t)((b * NKC + kc) * 16 + et)) * 64 + lane) * 8;
            const bf16x8 bh = *reinterpret_cast<const bf16x8*>(Bhi + bo);
            const bf16x8 bl = *reinterpret_cast<const bf16x8*>(Blo + bo);
            acc[0][et] = __builtin_amdgcn_mfma_f32_16x16x32_bf16(ah0, bh, acc[0][et], 0, 0, 0);
            acc[1][et] = __builtin_amdgcn_mfma_f32_16x16x32_bf16(ah1, bh, acc[1][et], 0, 0, 0);
            acc[0][et] = __builtin_amdgcn_mfma_f32_16x16x32_bf16(ah0, bl, acc[0][et], 0, 0, 0);
            acc[1][et] = __builtin_amdgcn_mfma_f32_16x16x32_bf16(ah1, bl, acc[1][et], 0, 0, 0);
            acc[0][et] = __builtin_amdgcn_mfma_f32_16x16x32_bf16(al0, bh, acc[0][et], 0, 0, 0);
            acc[1][et] = __builtin_amdgcn_mfma_f32_16x16x32_bf16(al1, bh, acc[1][et], 0, 0, 0);
        }
    }

    // ---------------- epilogue (wave-private): p[l] = sum_e G[l,e] * E[1+l,e] ----------------
    // C/D layout: col = lane&15 (e within tile), row = (lane>>4)*4 + i (l within tile) [verified r1-r13]
    #pragma unroll
    for (int s = 0; s < 2; ++s) {
        #pragma unroll
        for (int i = 0; i < 4; ++i) {
            const int l = l0 + s * 16 + lhi * 4 + i;      // always < 20000
            const float* Er = embt + (size_t)(1 + l) * EMBD + llo;
            float p = 0.f;
            #pragma unroll
            for (int et = 0; et < 16; ++et)
                p += acc[s][et][i] * Er[et * 16];
            p += __shfl_xor(p, 1);
            p += __shfl_xor(p, 2);
            p += __shfl_xor(p, 4);
            p += __shfl_xor(p, 8);
            if (llo == 0) out[(size_t)b * LMAX + l] = p;
        }
    }
}

// ---------------- Fallback (ws too small): straightforward f32 compute ----------------
__global__ __launch_bounds__(256)
void fallback_kernel(const float* __restrict__ attn, const float* __restrict__ sdelta,
                     const float* __restrict__ embt, const float* __restrict__ vw,
                     float* __restrict__ out) {
    const int idx = blockIdx.x * 256 + threadIdx.x;
    if (idx >= NB * LMAX) return;
    const int b = idx / LMAX;
    const int l = idx % LMAX;
    float s = 0.f;
    for (int m = 0; m < MLEN; ++m) {
        const float* ar = attn + ((size_t)b * MLEN + m) * EMBD;
        const float* er = embt + (size_t)(l + 1) * EMBD;
        float dot = 0.f;
        for (int e = 0; e < EMBD; ++e) dot += ar[e] * er[e];
        const size_t so = (((size_t)b * MLEN + m) * LMAX + l) * 2;
        s += dot * vw[m] * (sdelta[so] + sdelta[so + 1]);
    }
    out[idx] = s;
}

extern "C" void kernel_launch(void* const* d_in, const int* in_sizes, int n_in,
                              void* d_out, int out_size, void* d_ws, size_t ws_size,
                              hipStream_t stream) {
    const float* attn   = (const float*)d_in[0];  // [16][100][256] f32
    const float* sdelta = (const float*)d_in[1];  // [16][100][20000][2] f32
    // d_in[2] = traj_len — unused by the reference computation
    const float* embt   = (const float*)d_in[3];  // [20001][256] f32
    const float* vw     = (const float*)d_in[4];  // [1][100] f32
    float* out = (float*)d_out;                   // [16][20000] f32

    const size_t fragShorts = (size_t)PREP_TASKS * 8;                   // 524288 u16 per array
    const size_t needed     = 2 * fragShorts * sizeof(unsigned short);  // 2 MB

    if (ws_size >= needed) {
        unsigned short* Bhi = (unsigned short*)d_ws;
        unsigned short* Blo = Bhi + fragShorts;
        prep2_kernel<<<PREP_TASKS / 256, 256, 0, stream>>>(attn, vw, Bhi, Blo);
        main_kernel<<<NWAVES, 64, 0, stream>>>(Bhi, Blo, sdelta, embt, out);
    } else {
        fallback_kernel<<<(NB * LMAX + 255) / 256, 256, 0, stream>>>(attn, sdelta, embt, vw, out);
    }
}

// Round 15
// 157.806 us; speedup vs baseline: 2.0413x; 2.0413x over previous
//
#include <hip/hip_runtime.h>

// Problem constants: B=16, MAX_LEN=100, LOC_MAX=20000, EMB=256, D_DELTA=2
#define NB 16
#define MLEN 100
#define EMBD 256
#define LMAX 20000
#define LTILE 64            // l's per block
#define NLT 313             // ceil(20000/64)
#define NKC 4               // K chunks of 32 m's (100 zero-padded to 128)
#define FSTRIDE 520         // u16 per lsub sub-tile: 64 lanes * 8 + 8 pad
#define PREP_TASKS (NB * NKC * 16 * 64)   // 65536: (b,kc,etg,lane)

typedef __attribute__((ext_vector_type(4))) float f32x4;
typedef __attribute__((ext_vector_type(2))) float f32x2;
typedef __attribute__((ext_vector_type(8))) short bf16x8;

__device__ __forceinline__ unsigned short f2bf(float x) {
    union { float f; unsigned u; } a; a.f = x;
    unsigned r = a.u + 0x7FFFu + ((a.u >> 16) & 1u);
    return (unsigned short)(r >> 16);
}
__device__ __forceinline__ float bf2f(unsigned short h) {
    union { unsigned u; float f; } a; a.u = ((unsigned)h) << 16;
    return a.f;
}

// ---------------- Kernel 1: pack vwA = vw[m]*attn[b][m][e] into MFMA B-fragments (hi/lo) ----------------
// frag f = (b*NKC+kc)*16 + etg ; lane: e = etg*16 + (lane&15), k = (lane>>4)*8 + j, m = kc*32 + k
// m >= MLEN -> exact zero (pairs with clamped/duplicated A loads: those A values multiply zero B)
__global__ __launch_bounds__(256)
void prep2_kernel(const float* __restrict__ attn, const float* __restrict__ vw,
                  unsigned short* __restrict__ Bhi, unsigned short* __restrict__ Blo) {
    const int gid  = blockIdx.x * 256 + threadIdx.x;   // < 65536
    const int lane = gid & 63;
    const int f    = gid >> 6;
    const int etg  = f & 15;
    const int kcb  = f >> 4;
    const int kc   = kcb & 3;
    const int b    = kcb >> 2;
    const int e    = etg * 16 + (lane & 15);
    const int m0   = kc * 32 + (lane >> 4) * 8;
    unsigned h[8], l[8];
    #pragma unroll
    for (int j = 0; j < 8; ++j) {
        const int m = m0 + j;
        float x = 0.f;
        if (m < MLEN) x = vw[m] * attn[((size_t)b * MLEN + m) * EMBD + e];
        const unsigned short hh = f2bf(x);
        h[j] = hh;
        l[j] = f2bf(x - bf2f(hh));
    }
    uint4 hi = make_uint4(h[0]|(h[1]<<16), h[2]|(h[3]<<16), h[4]|(h[5]<<16), h[6]|(h[7]<<16));
    uint4 lo = make_uint4(l[0]|(l[1]<<16), l[2]|(l[3]<<16), l[4]|(l[5]<<16), l[6]|(l[7]<<16));
    reinterpret_cast<uint4*>(Bhi)[gid] = hi;
    reinterpret_cast<uint4*>(Blo)[gid] = lo;
}

// ---------------- Kernel 2: register-resident-B fused GEMM ----------------
// Block: 512 thr (8 waves) owns (b, 64 l's) and ALL 256 e's (sdelta read exactly once).
// Wave w owns e-slice [32w, 32w+32) = etg {2w, 2w+1}; its FULL B operand (2 etg x 4 kc x hi/lo
// = 16 frags = 64 VGPRs) is loaded ONCE at entry. kc-loop: writeA -> raw s_barrier(lgkm only)
// -> ds_read A + 24 MFMA vs register B -> issueA(kc+1). No global latency inside the loop.
__global__ __launch_bounds__(512, 2)
void main_kernel(const unsigned short* __restrict__ Bhi, const unsigned short* __restrict__ Blo,
                 const float* __restrict__ sdelta, const float* __restrict__ embt,
                 float* __restrict__ out) {
    __shared__ __align__(16) unsigned short AhL[2][4 * FSTRIDE];  // 2 x 4160 B
    __shared__ __align__(16) unsigned short AlL[2][4 * FSTRIDE];  // 2 x 4160 B
    __shared__ float red[512];                                    // 2048 B (total 18688 B)

    const int b    = blockIdx.x;
    const int lt   = blockIdx.y;
    const int l0   = lt * LTILE;
    const int w    = threadIdx.x >> 6;          // 0..7
    const int lane = threadIdx.x & 63;
    const int llo  = lane & 15;
    const int lhi  = lane >> 4;

    // ---- B: one burst, register-resident for the whole kernel ----
    bf16x8 Bh[2][4], Bl[2][4];                  // [local etg][kc] = 64 VGPRs
    #pragma unroll
    for (int t = 0; t < 2; ++t) {
        #pragma unroll
        for (int kc = 0; kc < NKC; ++kc) {
            const size_t bo = (((size_t)(b * NKC + kc) * 16 + (w * 2 + t)) * 64 + lane) * 8;
            Bh[t][kc] = *reinterpret_cast<const bf16x8*>(Bhi + bo);
            Bl[t][kc] = *reinterpret_cast<const bf16x8*>(Blo + bo);
        }
    }

    f32x4 acc[4][2];                            // [lsub][local etg] = 32 VGPRs
    #pragma unroll
    for (int ls = 0; ls < 4; ++ls) {
        acc[ls][0] = (f32x4){0.f, 0.f, 0.f, 0.f};
        acc[ls][1] = (f32x4){0.f, 0.f, 0.f, 0.f};
    }

    // lane owns one l (clamped on the 313th tile; OOB outputs masked at store)
    const int lcl = min(l0 + lane, LMAX - 1);
    const float* sdb = sdelta + (size_t)b * MLEN * (LMAX * 2);

    f32x2 vA[2][4];                             // 1-deep prefetch, 8 VGPRs
    auto issueA = [&](int kc) {
        const int q = kc & 1;
        #pragma unroll
        for (int jj = 0; jj < 4; ++jj) {
            const int m  = kc * 32 + w * 4 + jj;
            const int mc = (m < MLEN) ? m : (MLEN - 1);
            vA[q][jj] = *reinterpret_cast<const f32x2*>(sdb + (size_t)mc * (LMAX * 2) + lcl * 2);
        }
    };
    auto writeA = [&](int kc) {
        const int q  = kc & 1;
        const int ls = lane >> 4;
        const int ll = lane & 15;
        #pragma unroll
        for (int jj = 0; jj < 4; ++jj) {
            const int r32 = w * 4 + jj;
            const int m   = kc * 32 + r32;
            const float msk = (m < MLEN) ? 1.f : 0.f;
            const f32x2 v = vA[q][jj];
            const float s0 = (v[0] + v[1]) * msk;
            const unsigned short h0 = f2bf(s0);
            const unsigned short L0 = f2bf(s0 - bf2f(h0));
            const int kg = r32 >> 3, j = r32 & 7;
            const int i0 = ls * FSTRIDE + (ll | (kg << 4)) * 8 + j;
            AhL[q][i0] = h0;
            AlL[q][i0] = L0;
        }
    };

    issueA(0);
    #pragma unroll
    for (int kc = 0; kc < NKC; ++kc) {
        const int q = kc & 1;
        writeA(kc);                              // waits own prefetched chunk only
        asm volatile("s_waitcnt lgkmcnt(0)" ::: "memory");
        __builtin_amdgcn_sched_barrier(0);
        __builtin_amdgcn_s_barrier();            // raw barrier: no vmcnt drain
        __builtin_amdgcn_sched_barrier(0);

        if (kc + 1 < NKC) issueA(kc + 1);        // in flight across MFMA + next barrier
        __builtin_amdgcn_sched_barrier(0);

        #pragma unroll
        for (int ls = 0; ls < 4; ++ls) {
            const bf16x8 ah = *reinterpret_cast<const bf16x8*>(&AhL[q][ls * FSTRIDE + lane * 8]);
            const bf16x8 al = *reinterpret_cast<const bf16x8*>(&AlL[q][ls * FSTRIDE + lane * 8]);
            #pragma unroll
            for (int t = 0; t < 2; ++t) {
                acc[ls][t] = __builtin_amdgcn_mfma_f32_16x16x32_bf16(ah, Bh[t][kc], acc[ls][t], 0, 0, 0);
                acc[ls][t] = __builtin_amdgcn_mfma_f32_16x16x32_bf16(ah, Bl[t][kc], acc[ls][t], 0, 0, 0);
                acc[ls][t] = __builtin_amdgcn_mfma_f32_16x16x32_bf16(al, Bh[t][kc], acc[ls][t], 0, 0, 0);
            }
        }
        // no second barrier: buf q next written at kc+2, ordered by kc+1's barrier (r13-verified)
    }

    // ---------------- epilogue: p[l] += sum over this wave's 32 e's; block-reduce in LDS ----------------
    // C/D layout: col = lane&15 (e), row = (lane>>4)*4 + i (l)  [verified r1-r14]
    #pragma unroll
    for (int ls = 0; ls < 4; ++ls) {
        #pragma unroll
        for (int i = 0; i < 4; ++i) {
            const int l  = l0 + ls * 16 + lhi * 4 + i;
            const int lc = (l < LMAX) ? l : (LMAX - 1);
            const float* Er = embt + (size_t)(1 + lc) * EMBD + w * 32 + llo;
            float p = acc[ls][0][i] * Er[0] + acc[ls][1][i] * Er[16];
            p += __shfl_xor(p, 1);
            p += __shfl_xor(p, 2);
            p += __shfl_xor(p, 4);
            p += __shfl_xor(p, 8);
            if (llo == 0) red[w * 64 + ls * 16 + lhi * 4 + i] = p;
        }
    }
    __syncthreads();
    if (threadIdx.x < 64) {
        const int t = threadIdx.x;
        const int l = l0 + t;
        if (l < LMAX) {
            float s = 0.f;
            #pragma unroll
            for (int ww = 0; ww < 8; ++ww) s += red[ww * 64 + t];
            out[(size_t)b * LMAX + l] = s;
        }
    }
}

// ---------------- Fallback (ws too small): straightforward f32 compute ----------------
__global__ __launch_bounds__(256)
void fallback_kernel(const float* __restrict__ attn, const float* __restrict__ sdelta,
                     const float* __restrict__ embt, const float* __restrict__ vw,
                     float* __restrict__ out) {
    const int idx = blockIdx.x * 256 + threadIdx.x;
    if (idx >= NB * LMAX) return;
    const int b = idx / LMAX;
    const int l = idx % LMAX;
    float s = 0.f;
    for (int m = 0; m < MLEN; ++m) {
        const float* ar = attn + ((size_t)b * MLEN + m) * EMBD;
        const float* er = embt + (size_t)(l + 1) * EMBD;
        float dot = 0.f;
        for (int e = 0; e < EMBD; ++e) dot += ar[e] * er[e];
        const size_t so = (((size_t)b * MLEN + m) * LMAX + l) * 2;
        s += dot * vw[m] * (sdelta[so] + sdelta[so + 1]);
    }
    out[idx] = s;
}

extern "C" void kernel_launch(void* const* d_in, const int* in_sizes, int n_in,
                              void* d_out, int out_size, void* d_ws, size_t ws_size,
                              hipStream_t stream) {
    const float* attn   = (const float*)d_in[0];  // [16][100][256] f32
    const float* sdelta = (const float*)d_in[1];  // [16][100][20000][2] f32
    // d_in[2] = traj_len — unused by the reference computation
    const float* embt   = (const float*)d_in[3];  // [20001][256] f32
    const float* vw     = (const float*)d_in[4];  // [1][100] f32
    float* out = (float*)d_out;                   // [16][20000] f32

    const size_t fragShorts = (size_t)PREP_TASKS * 8;                   // 524288 u16 per array
    const size_t needed     = 2 * fragShorts * sizeof(unsigned short);  // 2 MB

    if (ws_size >= needed) {
        unsigned short* Bhi = (unsigned short*)d_ws;
        unsigned short* Blo = Bhi + fragShorts;
        prep2_kernel<<<PREP_TASKS / 256, 256, 0, stream>>>(attn, vw, Bhi, Blo);
        main_kernel<<<dim3(NB, NLT), 512, 0, stream>>>(Bhi, Blo, sdelta, embt, out);
    } else {
        fallback_kernel<<<(NB * LMAX + 255) / 256, 256, 0, stream>>>(attn, sdelta, embt, vw, out);
    }
}

// Round 16
// 77.585 us; speedup vs baseline: 4.1520x; 2.0340x over previous
//
#include <hip/hip_runtime.h>

// Problem constants: B=16, MAX_LEN=100, LOC_MAX=20000, EMB=256, D_DELTA=2
#define NB 16
#define MLEN 100
#define EMBD 256
#define LMAX 20000
#define LTILE 64            // l's per block
#define NLT 313             // ceil(20000/64)
#define NKC 4               // K chunks of 32 m's (100 zero-padded to 128 in B)
#define FSTRIDE 520         // u16 per lsub sub-tile: 64 lanes * 8 + 8 pad
#define PREP_TASKS (NB * NKC * 16 * 64)   // 65536: (b,kc,etg,lane)

typedef __attribute__((ext_vector_type(4))) float f32x4;
typedef __attribute__((ext_vector_type(2))) float f32x2;
typedef _Float16 f16x8 __attribute__((ext_vector_type(8)));

__device__ __forceinline__ unsigned short f2h(float x) {
    union { _Float16 f; unsigned short u; } a; a.f = (_Float16)x; return a.u;
}

// ---------------- Kernel 1: pack vwA = vw[m]*attn[b][m][e] into single-f16 MFMA B-fragments ----------------
// frag f = (b*NKC+kc)*16 + etg ; lane: e = etg*16 + (lane&15), k = (lane>>4)*8 + j, m = kc*32 + k
// m >= MLEN -> exact zero (m-padding column; multiplies anything in A harmlessly)
__global__ __launch_bounds__(256)
void prep2_kernel(const float* __restrict__ attn, const float* __restrict__ vw,
                  unsigned short* __restrict__ Bf) {
    const int gid  = blockIdx.x * 256 + threadIdx.x;   // < 65536
    const int lane = gid & 63;
    const int f    = gid >> 6;
    const int etg  = f & 15;
    const int kcb  = f >> 4;
    const int kc   = kcb & 3;
    const int b    = kcb >> 2;
    const int e    = etg * 16 + (lane & 15);
    const int m0   = kc * 32 + (lane >> 4) * 8;
    unsigned h[8];
    #pragma unroll
    for (int j = 0; j < 8; ++j) {
        const int m = m0 + j;
        float x = 0.f;
        if (m < MLEN) x = vw[m] * attn[((size_t)b * MLEN + m) * EMBD + e];
        h[j] = f2h(x);
    }
    uint4 hi = make_uint4(h[0]|(h[1]<<16), h[2]|(h[3]<<16), h[4]|(h[5]<<16), h[6]|(h[7]<<16));
    reinterpret_cast<uint4*>(Bf)[gid] = hi;
}

// ---------------- Kernel 2: single-pass f16 GEMM G[l,e]=sum_m ds[m,l]*vwA[m,e]; epilogue dot E ----------------
// Structure = R13 (verified): block (b, 64 l's), 4 waves, wave w owns e-range [w*64,+64).
// Per kc: writeA -> raw s_barrier (lgkmcnt only, no vmcnt drain) -> 16 MFMA vs reg-B -> prefetch
// A(kc+1) + B(kc+1). 16 MFMAs/kc/wave (was 48), 4 B-loads (was 8, now prefetched off crit path).
__global__ __launch_bounds__(256, 3)
void main_kernel(const unsigned short* __restrict__ Bf,
                 const float* __restrict__ sdelta, const float* __restrict__ embt,
                 float* __restrict__ out) {
    __shared__ __align__(16) unsigned short AhL[2][4 * FSTRIDE];  // 2 x 4160 B
    __shared__ float red[256];                                    // 1024 B (total 9344 B)

    const int b    = blockIdx.x;
    const int lt0  = blockIdx.y;
    const int l0   = lt0 * LTILE;
    const int w    = threadIdx.x >> 6;
    const int lane = threadIdx.x & 63;
    const int llo  = lane & 15;
    const int lhi  = lane >> 4;

    f32x4 acc[4][4];
    #pragma unroll
    for (int lt = 0; lt < 4; ++lt)
        #pragma unroll
        for (int et = 0; et < 4; ++et)
            acc[lt][et] = (f32x4){0.f, 0.f, 0.f, 0.f};

    // per-lane global source: lane owns ONE l, clamped for edge tile (332nd tile cols masked at store)
    const int lcl = min(l0 + lane, LMAX - 1);

    f32x2 vA[2][8];
    auto issueA = [&](int kc) {
        const int q = kc & 1;
        #pragma unroll
        for (int jj = 0; jj < 8; ++jj) {
            const int m  = kc * 32 + jj * 4 + w;
            const int mc = (m < MLEN) ? m : (MLEN - 1);
            vA[q][jj] = *reinterpret_cast<const f32x2*>(
                            sdelta + ((size_t)(b * MLEN + mc) * LMAX + lcl) * 2);
        }
    };
    // pair-sum -> single f16 -> LDS A-fragment order (auto counted-vmcnt wait on vA[q] only)
    auto writeA = [&](int kc) {
        const int q  = kc & 1;
        const int lt = lane >> 4;
        const int ll = lane & 15;
        #pragma unroll
        for (int jj = 0; jj < 8; ++jj) {
            const int r32 = jj * 4 + w;
            const int m   = kc * 32 + r32;
            const float msk = (m < MLEN) ? 1.f : 0.f;
            const f32x2 v = vA[q][jj];
            const int kg = r32 >> 3, j = r32 & 7;
            AhL[q][lt * FSTRIDE + (ll | (kg << 4)) * 8 + j] = f2h((v[0] + v[1]) * msk);
        }
    };
    auto loadB = [&](int kc, f16x8* dst) {
        #pragma unroll
        for (int et = 0; et < 4; ++et) {
            const size_t bo = (((size_t)(b * NKC + kc) * 16 + (w * 4 + et)) * 64 + lane) * 8;
            dst[et] = *reinterpret_cast<const f16x8*>(Bf + bo);
        }
    };

    f16x8 Bc[4], Bn[4];
    issueA(0);
    loadB(0, Bc);
    #pragma unroll
    for (int kc = 0; kc < NKC; ++kc) {
        const int q = kc & 1;
        writeA(kc);                              // waits own prefetched chunk only (counted)
        asm volatile("s_waitcnt lgkmcnt(0)" ::: "memory");
        __builtin_amdgcn_sched_barrier(0);
        __builtin_amdgcn_s_barrier();            // raw barrier: no vmcnt drain
        __builtin_amdgcn_sched_barrier(0);

        if (kc + 1 < NKC) {
            issueA(kc + 1);                      // in flight across MFMA + next barrier
            loadB(kc + 1, Bn);                   // B prefetch: off the post-barrier critical path
        }
        __builtin_amdgcn_sched_barrier(0);

        #pragma unroll
        for (int lt = 0; lt < 4; ++lt) {
            const f16x8 ah = *reinterpret_cast<const f16x8*>(&AhL[q][lt * FSTRIDE + lane * 8]);
            #pragma unroll
            for (int et = 0; et < 4; ++et)
                acc[lt][et] = __builtin_amdgcn_mfma_f32_16x16x32_f16(ah, Bc[et], acc[lt][et], 0, 0, 0);
        }
        if (kc + 1 < NKC) { Bc[0] = Bn[0]; Bc[1] = Bn[1]; Bc[2] = Bn[2]; Bc[3] = Bn[3]; }
        // no second barrier: buf q next written at kc+2, ordered by kc+1's barrier (r13-verified)
    }

    // ---------------- epilogue: p[l] = sum_e G[l,e] * E[1+l, e] ----------------
    // C/D layout: col = lane&15 (e), row = (lane>>4)*4 + i (l)  [verified r1-r15]
    float p[4][4];
    #pragma unroll
    for (int lt = 0; lt < 4; ++lt) {
        #pragma unroll
        for (int i = 0; i < 4; ++i) {
            const int l  = l0 + lt * 16 + lhi * 4 + i;
            const int lc = (l < LMAX) ? l : (LMAX - 1);
            const float* Er = embt + (size_t)(1 + lc) * EMBD + w * 64 + llo;
            float s = acc[lt][0][i] * Er[0];
            s += acc[lt][1][i] * Er[16];
            s += acc[lt][2][i] * Er[32];
            s += acc[lt][3][i] * Er[48];
            p[lt][i] = s;
        }
    }
    #pragma unroll
    for (int lt = 0; lt < 4; ++lt)
        #pragma unroll
        for (int i = 0; i < 4; ++i) {
            float x = p[lt][i];
            x += __shfl_xor(x, 1);
            x += __shfl_xor(x, 2);
            x += __shfl_xor(x, 4);
            x += __shfl_xor(x, 8);
            p[lt][i] = x;
        }
    if (llo == 0) {
        #pragma unroll
        for (int lt = 0; lt < 4; ++lt)
            *reinterpret_cast<float4*>(&red[w * 64 + lt * 16 + lhi * 4]) =
                make_float4(p[lt][0], p[lt][1], p[lt][2], p[lt][3]);
    }
    __syncthreads();
    if (threadIdx.x < 64) {
        const int t = threadIdx.x;
        const int l = l0 + t;
        if (l < LMAX) {
            out[(size_t)b * LMAX + l] = red[t] + red[64 + t] + red[128 + t] + red[192 + t];
        }
    }
}

// ---------------- Fallback (ws too small): straightforward f32 compute ----------------
__global__ __launch_bounds__(256)
void fallback_kernel(const float* __restrict__ attn, const float* __restrict__ sdelta,
                     const float* __restrict__ embt, const float* __restrict__ vw,
                     float* __restrict__ out) {
    const int idx = blockIdx.x * 256 + threadIdx.x;
    if (idx >= NB * LMAX) return;
    const int b = idx / LMAX;
    const int l = idx % LMAX;
    float s = 0.f;
    for (int m = 0; m < MLEN; ++m) {
        const float* ar = attn + ((size_t)b * MLEN + m) * EMBD;
        const float* er = embt + (size_t)(l + 1) * EMBD;
        float dot = 0.f;
        for (int e = 0; e < EMBD; ++e) dot += ar[e] * er[e];
        const size_t so = (((size_t)b * MLEN + m) * LMAX + l) * 2;
        s += dot * vw[m] * (sdelta[so] + sdelta[so + 1]);
    }
    out[idx] = s;
}

extern "C" void kernel_launch(void* const* d_in, const int* in_sizes, int n_in,
                              void* d_out, int out_size, void* d_ws, size_t ws_size,
                              hipStream_t stream) {
    const float* attn   = (const float*)d_in[0];  // [16][100][256] f32
    const float* sdelta = (const float*)d_in[1];  // [16][100][20000][2] f32
    // d_in[2] = traj_len — unused by the reference computation
    const float* embt   = (const float*)d_in[3];  // [20001][256] f32
    const float* vw     = (const float*)d_in[4];  // [1][100] f32
    float* out = (float*)d_out;                   // [16][20000] f32

    const size_t fragShorts = (size_t)PREP_TASKS * 8;                // 524288 u16
    const size_t needed     = fragShorts * sizeof(unsigned short);   // 1 MB

    if (ws_size >= needed) {
        unsigned short* Bf = (unsigned short*)d_ws;
        prep2_kernel<<<PREP_TASKS / 256, 256, 0, stream>>>(attn, vw, Bf);
        main_kernel<<<dim3(NB, NLT), 256, 0, stream>>>(Bf, sdelta, embt, out);
    } else {
        fallback_kernel<<<(NB * LMAX + 255) / 256, 256, 0, stream>>>(attn, sdelta, embt, vw, out);
    }
}

// Round 17
// 75.231 us; speedup vs baseline: 4.2820x; 1.0313x over previous
//
#include <hip/hip_runtime.h>

// Problem constants: B=16, MAX_LEN=100, LOC_MAX=20000, EMB=256, D_DELTA=2
#define NB 16
#define MLEN 100
#define EMBD 256
#define LMAX 20000
#define LTILE 128           // l's per block (lane owns an l-pair)
#define NLT 157             // ceil(20000/128)
#define NKC 4               // K chunks of 32 m's (100 zero-padded to 128 in B)
#define FSTRIDE 520         // u16 per lsub sub-tile: 512 data + 8 pad (1040 B, 16B-aligned)
#define PREP_TASKS (NB * NKC * 16 * 64)   // 65536: (b,kc,etg,lane)

typedef __attribute__((ext_vector_type(4))) float f32x4;
typedef _Float16 f16x8 __attribute__((ext_vector_type(8)));

__device__ __forceinline__ unsigned short f2h(float x) {
    union { _Float16 f; unsigned short u; } a; a.f = (_Float16)x; return a.u;
}

// ---------------- Kernel 1: pack vwA = vw[m]*attn[b][m][e] into single-f16 MFMA B-fragments ----------------
// frag f = (b*NKC+kc)*16 + etg ; lane: e = etg*16 + (lane&15), k = (lane>>4)*8 + j, m = kc*32 + k
// m >= MLEN -> exact zero
__global__ __launch_bounds__(256)
void prep2_kernel(const float* __restrict__ attn, const float* __restrict__ vw,
                  unsigned short* __restrict__ Bf) {
    const int gid  = blockIdx.x * 256 + threadIdx.x;   // < 65536
    const int lane = gid & 63;
    const int f    = gid >> 6;
    const int etg  = f & 15;
    const int kcb  = f >> 4;
    const int kc   = kcb & 3;
    const int b    = kcb >> 2;
    const int e    = etg * 16 + (lane & 15);
    const int m0   = kc * 32 + (lane >> 4) * 8;
    unsigned h[8];
    #pragma unroll
    for (int j = 0; j < 8; ++j) {
        const int m = m0 + j;
        float x = 0.f;
        if (m < MLEN) x = vw[m] * attn[((size_t)b * MLEN + m) * EMBD + e];
        h[j] = f2h(x);
    }
    uint4 hi = make_uint4(h[0]|(h[1]<<16), h[2]|(h[3]<<16), h[4]|(h[5]<<16), h[6]|(h[7]<<16));
    reinterpret_cast<uint4*>(Bf)[gid] = hi;
}

// ---------------- Kernel 2: single-pass f16 GEMM, LTILE=128, b128 A-staging ----------------
// Block: (b, 128 l's), 4 waves; wave w owns e-range [w*64,+64). K = 100 m's in 4 chunks of 32.
// Wave-row-block staging: wave w stages rows kc*32 + w*8 .. +7; lane owns l-pair (2*lane, 2*lane+1);
// its 8 f16 per l are LDS-contiguous -> 2 x ds_write_b128 per kc (was 16 x b16).
// Per kc: writeA -> raw s_barrier (lgkmcnt only) -> 32 MFMA vs prefetched reg-B -> issueA/loadB(kc+1).
__global__ __launch_bounds__(256, 2)
void main_kernel(const unsigned short* __restrict__ Bf,
                 const float* __restrict__ sdelta, const float* __restrict__ embt,
                 float* __restrict__ out) {
    __shared__ __align__(16) unsigned short AhL[2][8 * FSTRIDE];  // 2 x 8320 B
    __shared__ float red[512];                                    // 2048 B (total 18688 B)

    const int b    = blockIdx.x;
    const int lt0  = blockIdx.y;
    const int l0   = lt0 * LTILE;
    const int w    = threadIdx.x >> 6;
    const int lane = threadIdx.x & 63;
    const int llo  = lane & 15;
    const int lhi  = lane >> 4;

    f32x4 acc[8][4];
    #pragma unroll
    for (int lt = 0; lt < 8; ++lt)
        #pragma unroll
        for (int et = 0; et < 4; ++et)
            acc[lt][et] = (f32x4){0.f, 0.f, 0.f, 0.f};

    // per-lane global source: 2 consecutive l's (one f32x4), clamped for the edge tile
    const int lcl = min(l0 + 2 * lane, LMAX - 2);

    f32x4 vA[2][8];
    // wave w loads rows r32 = w*8 + jj (8 consecutive rows), each lane its l-pair (16B coalesced)
    auto issueA = [&](int kc) {
        const int q = kc & 1;
        #pragma unroll
        for (int jj = 0; jj < 8; ++jj) {
            const int m  = kc * 32 + w * 8 + jj;
            const int mc = (m < MLEN) ? m : (MLEN - 1);
            vA[q][jj] = *reinterpret_cast<const f32x4*>(
                            sdelta + ((size_t)(b * MLEN + mc) * LMAX + lcl) * 2);
        }
    };
    // pair-sum -> f16; lane's 8 j-elements contiguous -> 2 x ds_write_b128 (l even, l odd)
    auto writeA = [&](int kc) {
        const int q   = kc & 1;
        const int lt  = lane >> 3;          // lsub of this lane's l-pair
        const int lo0 = (2 * lane) & 15;    // row (l) within 16-tile, even
        unsigned h0[8], h1[8];
        #pragma unroll
        for (int jj = 0; jj < 8; ++jj) {
            const int m = kc * 32 + w * 8 + jj;
            const float msk = (m < MLEN) ? 1.f : 0.f;
            const f32x4 v = vA[q][jj];
            h0[jj] = f2h((v[0] + v[1]) * msk);
            h1[jj] = f2h((v[2] + v[3]) * msk);
        }
        const int i0 = lt * FSTRIDE + (lo0 | (w << 4)) * 8;   // kg == w
        *reinterpret_cast<uint4*>(&AhL[q][i0]) =
            make_uint4(h0[0]|(h0[1]<<16), h0[2]|(h0[3]<<16), h0[4]|(h0[5]<<16), h0[6]|(h0[7]<<16));
        *reinterpret_cast<uint4*>(&AhL[q][i0 + 8]) =
            make_uint4(h1[0]|(h1[1]<<16), h1[2]|(h1[3]<<16), h1[4]|(h1[5]<<16), h1[6]|(h1[7]<<16));
    };
    auto loadB = [&](int kc, f16x8* dst) {
        #pragma unroll
        for (int et = 0; et < 4; ++et) {
            const size_t bo = (((size_t)(b * NKC + kc) * 16 + (w * 4 + et)) * 64 + lane) * 8;
            dst[et] = *reinterpret_cast<const f16x8*>(Bf + bo);
        }
    };

    f16x8 Bc[4], Bn[4];
    issueA(0);
    loadB(0, Bc);
    #pragma unroll
    for (int kc = 0; kc < NKC; ++kc) {
        const int q = kc & 1;
        writeA(kc);                              // waits own prefetched chunk only (counted)
        asm volatile("s_waitcnt lgkmcnt(0)" ::: "memory");
        __builtin_amdgcn_sched_barrier(0);
        __builtin_amdgcn_s_barrier();            // raw barrier: no vmcnt drain
        __builtin_amdgcn_sched_barrier(0);

        if (kc + 1 < NKC) {
            issueA(kc + 1);                      // in flight across MFMA + next barrier
            loadB(kc + 1, Bn);                   // B prefetch off the post-barrier critical path
        }
        __builtin_amdgcn_sched_barrier(0);

        #pragma unroll
        for (int lt = 0; lt < 8; ++lt) {
            const f16x8 ah = *reinterpret_cast<const f16x8*>(&AhL[q][lt * FSTRIDE + lane * 8]);
            #pragma unroll
            for (int et = 0; et < 4; ++et)
                acc[lt][et] = __builtin_amdgcn_mfma_f32_16x16x32_f16(ah, Bc[et], acc[lt][et], 0, 0, 0);
        }
        if (kc + 1 < NKC) { Bc[0] = Bn[0]; Bc[1] = Bn[1]; Bc[2] = Bn[2]; Bc[3] = Bn[3]; }
        // no second barrier: buf q next written at kc+2, ordered by kc+1's barrier (r13/r16-verified)
    }

    // ---------------- epilogue: p[l] = sum_e G[l,e] * E[1+l, e] ----------------
    // C/D layout: col = lane&15 (e), row = (lane>>4)*4 + i (l)  [verified r1-r16]
    float p[8][4];
    #pragma unroll
    for (int lt = 0; lt < 8; ++lt) {
        #pragma unroll
        for (int i = 0; i < 4; ++i) {
            const int l  = l0 + lt * 16 + lhi * 4 + i;
            const int lc = (l < LMAX) ? l : (LMAX - 1);
            const float* Er = embt + (size_t)(1 + lc) * EMBD + w * 64 + llo;
            float s = acc[lt][0][i] * Er[0];
            s += acc[lt][1][i] * Er[16];
            s += acc[lt][2][i] * Er[32];
            s += acc[lt][3][i] * Er[48];
            p[lt][i] = s;
        }
    }
    #pragma unroll
    for (int lt = 0; lt < 8; ++lt)
        #pragma unroll
        for (int i = 0; i < 4; ++i) {
            float x = p[lt][i];
            x += __shfl_xor(x, 1);
            x += __shfl_xor(x, 2);
            x += __shfl_xor(x, 4);
            x += __shfl_xor(x, 8);
            p[lt][i] = x;
        }
    if (llo == 0) {
        #pragma unroll
        for (int lt = 0; lt < 8; ++lt)
            *reinterpret_cast<float4*>(&red[w * 128 + lt * 16 + lhi * 4]) =
                make_float4(p[lt][0], p[lt][1], p[lt][2], p[lt][3]);
    }
    __syncthreads();
    if (threadIdx.x < 128) {
        const int t = threadIdx.x;
        const int l = l0 + t;
        if (l < LMAX) {
            out[(size_t)b * LMAX + l] = red[t] + red[128 + t] + red[256 + t] + red[384 + t];
        }
    }
}

// ---------------- Fallback (ws too small): straightforward f32 compute ----------------
__global__ __launch_bounds__(256)
void fallback_kernel(const float* __restrict__ attn, const float* __restrict__ sdelta,
                     const float* __restrict__ embt, const float* __restrict__ vw,
                     float* __restrict__ out) {
    const int idx = blockIdx.x * 256 + threadIdx.x;
    if (idx >= NB * LMAX) return;
    const int b = idx / LMAX;
    const int l = idx % LMAX;
    float s = 0.f;
    for (int m = 0; m < MLEN; ++m) {
        const float* ar = attn + ((size_t)b * MLEN + m) * EMBD;
        const float* er = embt + (size_t)(l + 1) * EMBD;
        float dot = 0.f;
        for (int e = 0; e < EMBD; ++e) dot += ar[e] * er[e];
        const size_t so = (((size_t)b * MLEN + m) * LMAX + l) * 2;
        s += dot * vw[m] * (sdelta[so] + sdelta[so + 1]);
    }
    out[idx] = s;
}

extern "C" void kernel_launch(void* const* d_in, const int* in_sizes, int n_in,
                              void* d_out, int out_size, void* d_ws, size_t ws_size,
                              hipStream_t stream) {
    const float* attn   = (const float*)d_in[0];  // [16][100][256] f32
    const float* sdelta = (const float*)d_in[1];  // [16][100][20000][2] f32
    // d_in[2] = traj_len — unused by the reference computation
    const float* embt   = (const float*)d_in[3];  // [20001][256] f32
    const float* vw     = (const float*)d_in[4];  // [1][100] f32
    float* out = (float*)d_out;                   // [16][20000] f32

    const size_t fragShorts = (size_t)PREP_TASKS * 8;                // 524288 u16
    const size_t needed     = fragShorts * sizeof(unsigned short);   // 1 MB

    if (ws_size >= needed) {
        unsigned short* Bf = (unsigned short*)d_ws;
        prep2_kernel<<<PREP_TASKS / 256, 256, 0, stream>>>(attn, vw, Bf);
        main_kernel<<<dim3(NB, NLT), 256, 0, stream>>>(Bf, sdelta, embt, out);
    } else {
        fallback_kernel<<<(NB * LMAX + 255) / 256, 256, 0, stream>>>(attn, sdelta, embt, vw, out);
    }
}

// Round 18
// 72.409 us; speedup vs baseline: 4.4488x; 1.0390x over previous
//
#include <hip/hip_runtime.h>

// Problem constants: B=16, MAX_LEN=100, LOC_MAX=20000, EMB=256, D_DELTA=2
#define NB 16
#define MLEN 100
#define EMBD 256
#define LMAX 20000
#define LTILE 128           // l's per block (lane owns an l-pair)
#define NLT 157             // ceil(20000/128)
#define NKC 4               // K chunks of 32 m's (100 zero-padded to 128 in B)
#define FSTRIDE 520         // u16 per lsub sub-tile: 512 data + 8 pad (1040 B, 16B-aligned)
#define PREP_TASKS (NB * NKC * 16 * 64)   // 65536: (b,kc,etg,lane)

typedef __attribute__((ext_vector_type(4))) float f32x4;
typedef _Float16 f16x8 __attribute__((ext_vector_type(8)));

__device__ __forceinline__ unsigned short f2h(float x) {
    union { _Float16 f; unsigned short u; } a; a.f = (_Float16)x; return a.u;
}

// ---------------- Kernel 1: pack vwA = vw[m]*attn[b][m][e] into single-f16 MFMA B-fragments ----------------
// frag f = (b*NKC+kc)*16 + etg ; lane: e = etg*16 + (lane&15), k = (lane>>4)*8 + j, m = kc*32 + k
// m >= MLEN -> exact zero
__global__ __launch_bounds__(256)
void prep2_kernel(const float* __restrict__ attn, const float* __restrict__ vw,
                  unsigned short* __restrict__ Bf) {
    const int gid  = blockIdx.x * 256 + threadIdx.x;   // < 65536
    const int lane = gid & 63;
    const int f    = gid >> 6;
    const int etg  = f & 15;
    const int kcb  = f >> 4;
    const int kc   = kcb & 3;
    const int b    = kcb >> 2;
    const int e    = etg * 16 + (lane & 15);
    const int m0   = kc * 32 + (lane >> 4) * 8;
    unsigned h[8];
    #pragma unroll
    for (int j = 0; j < 8; ++j) {
        const int m = m0 + j;
        float x = 0.f;
        if (m < MLEN) x = vw[m] * attn[((size_t)b * MLEN + m) * EMBD + e];
        h[j] = f2h(x);
    }
    uint4 hi = make_uint4(h[0]|(h[1]<<16), h[2]|(h[3]<<16), h[4]|(h[5]<<16), h[6]|(h[7]<<16));
    reinterpret_cast<uint4*>(Bf)[gid] = hi;
}

// ---------------- Kernel 2: single-pass f16 GEMM, LTILE=128, 2-phase-deep A prefetch ----------------
// Block: (b, 128 l's), 4 waves; wave w owns e-range [w*64,+64). K = 100 m's in 4 chunks of 32.
// Pipeline (per kc): writeA(kc) [consumes slot q] -> issueA(kc+2) into freed slot q [BEFORE the
// barrier: ~2 phases of latency cover] -> raw s_barrier (lgkmcnt only, no vmcnt drain) ->
// loadB(kc+1) -> 32 MFMA vs reg-B. vA[2] slots, zero extra registers vs R17.
__global__ __launch_bounds__(256, 2)
void main_kernel(const unsigned short* __restrict__ Bf,
                 const float* __restrict__ sdelta, const float* __restrict__ embt,
                 float* __restrict__ out) {
    __shared__ __align__(16) unsigned short AhL[2][8 * FSTRIDE];  // 2 x 8320 B
    __shared__ float red[512];                                    // 2048 B (total 18688 B)

    const int b    = blockIdx.x;
    const int lt0  = blockIdx.y;
    const int l0   = lt0 * LTILE;
    const int w    = threadIdx.x >> 6;
    const int lane = threadIdx.x & 63;
    const int llo  = lane & 15;
    const int lhi  = lane >> 4;

    f32x4 acc[8][4];
    #pragma unroll
    for (int lt = 0; lt < 8; ++lt)
        #pragma unroll
        for (int et = 0; et < 4; ++et)
            acc[lt][et] = (f32x4){0.f, 0.f, 0.f, 0.f};

    // per-lane global source: 2 consecutive l's (one f32x4), clamped for the edge tile
    const int lcl = min(l0 + 2 * lane, LMAX - 2);

    f32x4 vA[2][8];
    // wave w loads rows r32 = w*8 + jj (8 consecutive rows), each lane its l-pair (16B coalesced)
    auto issueA = [&](int kc) {
        const int q = kc & 1;
        #pragma unroll
        for (int jj = 0; jj < 8; ++jj) {
            const int m  = kc * 32 + w * 8 + jj;
            const int mc = (m < MLEN) ? m : (MLEN - 1);
            vA[q][jj] = *reinterpret_cast<const f32x4*>(
                            sdelta + ((size_t)(b * MLEN + mc) * LMAX + lcl) * 2);
        }
    };
    // pair-sum -> f16; lane's 8 j-elements contiguous -> 2 x ds_write_b128 (l even, l odd)
    auto writeA = [&](int kc) {
        const int q   = kc & 1;
        const int lt  = lane >> 3;          // lsub of this lane's l-pair
        const int lo0 = (2 * lane) & 15;    // row (l) within 16-tile, even
        unsigned h0[8], h1[8];
        #pragma unroll
        for (int jj = 0; jj < 8; ++jj) {
            const int m = kc * 32 + w * 8 + jj;
            const float msk = (m < MLEN) ? 1.f : 0.f;
            const f32x4 v = vA[q][jj];
            h0[jj] = f2h((v[0] + v[1]) * msk);
            h1[jj] = f2h((v[2] + v[3]) * msk);
        }
        const int i0 = lt * FSTRIDE + (lo0 | (w << 4)) * 8;   // kg == w
        *reinterpret_cast<uint4*>(&AhL[q][i0]) =
            make_uint4(h0[0]|(h0[1]<<16), h0[2]|(h0[3]<<16), h0[4]|(h0[5]<<16), h0[6]|(h0[7]<<16));
        *reinterpret_cast<uint4*>(&AhL[q][i0 + 8]) =
            make_uint4(h1[0]|(h1[1]<<16), h1[2]|(h1[3]<<16), h1[4]|(h1[5]<<16), h1[6]|(h1[7]<<16));
    };
    auto loadB = [&](int kc, f16x8* dst) {
        #pragma unroll
        for (int et = 0; et < 4; ++et) {
            const size_t bo = (((size_t)(b * NKC + kc) * 16 + (w * 4 + et)) * 64 + lane) * 8;
            dst[et] = *reinterpret_cast<const f16x8*>(Bf + bo);
        }
    };

    f16x8 Bc[4], Bn[4];
    issueA(0);                                   // slot 0 in flight
    issueA(1);                                   // slot 1 in flight
    loadB(0, Bc);
    #pragma unroll
    for (int kc = 0; kc < NKC; ++kc) {
        const int q = kc & 1;
        writeA(kc);                              // counted wait on slot q only
        if (kc + 2 < NKC) issueA(kc + 2);        // refill freed slot q BEFORE barrier: 2-phase cover
        __builtin_amdgcn_sched_barrier(0);
        asm volatile("s_waitcnt lgkmcnt(0)" ::: "memory");
        __builtin_amdgcn_sched_barrier(0);
        __builtin_amdgcn_s_barrier();            // raw barrier: no vmcnt drain
        __builtin_amdgcn_sched_barrier(0);

        if (kc + 1 < NKC) loadB(kc + 1, Bn);     // B prefetch (L2-resident) during MFMA window
        __builtin_amdgcn_sched_barrier(0);

        #pragma unroll
        for (int lt = 0; lt < 8; ++lt) {
            const f16x8 ah = *reinterpret_cast<const f16x8*>(&AhL[q][lt * FSTRIDE + lane * 8]);
            #pragma unroll
            for (int et = 0; et < 4; ++et)
                acc[lt][et] = __builtin_amdgcn_mfma_f32_16x16x32_f16(ah, Bc[et], acc[lt][et], 0, 0, 0);
        }
        if (kc + 1 < NKC) { Bc[0] = Bn[0]; Bc[1] = Bn[1]; Bc[2] = Bn[2]; Bc[3] = Bn[3]; }
        // no second barrier: buf q next written at kc+2, ordered by kc+1's barrier (r13/r16-verified)
    }

    // ---------------- epilogue: p[l] = sum_e G[l,e] * E[1+l, e] ----------------
    // C/D layout: col = lane&15 (e), row = (lane>>4)*4 + i (l)  [verified r1-r17]
    float p[8][4];
    #pragma unroll
    for (int lt = 0; lt < 8; ++lt) {
        #pragma unroll
        for (int i = 0; i < 4; ++i) {
            const int l  = l0 + lt * 16 + lhi * 4 + i;
            const int lc = (l < LMAX) ? l : (LMAX - 1);
            const float* Er = embt + (size_t)(1 + lc) * EMBD + w * 64 + llo;
            float s = acc[lt][0][i] * Er[0];
            s += acc[lt][1][i] * Er[16];
            s += acc[lt][2][i] * Er[32];
            s += acc[lt][3][i] * Er[48];
            p[lt][i] = s;
        }
    }
    #pragma unroll
    for (int lt = 0; lt < 8; ++lt)
        #pragma unroll
        for (int i = 0; i < 4; ++i) {
            float x = p[lt][i];
            x += __shfl_xor(x, 1);
            x += __shfl_xor(x, 2);
            x += __shfl_xor(x, 4);
            x += __shfl_xor(x, 8);
            p[lt][i] = x;
        }
    if (llo == 0) {
        #pragma unroll
        for (int lt = 0; lt < 8; ++lt)
            *reinterpret_cast<float4*>(&red[w * 128 + lt * 16 + lhi * 4]) =
                make_float4(p[lt][0], p[lt][1], p[lt][2], p[lt][3]);
    }
    __syncthreads();
    if (threadIdx.x < 128) {
        const int t = threadIdx.x;
        const int l = l0 + t;
        if (l < LMAX) {
            out[(size_t)b * LMAX + l] = red[t] + red[128 + t] + red[256 + t] + red[384 + t];
        }
    }
}

// ---------------- Fallback (ws too small): straightforward f32 compute ----------------
__global__ __launch_bounds__(256)
void fallback_kernel(const float* __restrict__ attn, const float* __restrict__ sdelta,
                     const float* __restrict__ embt, const float* __restrict__ vw,
                     float* __restrict__ out) {
    const int idx = blockIdx.x * 256 + threadIdx.x;
    if (idx >= NB * LMAX) return;
    const int b = idx / LMAX;
    const int l = idx % LMAX;
    float s = 0.f;
    for (int m = 0; m < MLEN; ++m) {
        const float* ar = attn + ((size_t)b * MLEN + m) * EMBD;
        const float* er = embt + (size_t)(l + 1) * EMBD;
        float dot = 0.f;
        for (int e = 0; e < EMBD; ++e) dot += ar[e] * er[e];
        const size_t so = (((size_t)b * MLEN + m) * LMAX + l) * 2;
        s += dot * vw[m] * (sdelta[so] + sdelta[so + 1]);
    }
    out[idx] = s;
}

extern "C" void kernel_launch(void* const* d_in, const int* in_sizes, int n_in,
                              void* d_out, int out_size, void* d_ws, size_t ws_size,
                              hipStream_t stream) {
    const float* attn   = (const float*)d_in[0];  // [16][100][256] f32
    const float* sdelta = (const float*)d_in[1];  // [16][100][20000][2] f32
    // d_in[2] = traj_len — unused by the reference computation
    const float* embt   = (const float*)d_in[3];  // [20001][256] f32
    const float* vw     = (const float*)d_in[4];  // [1][100] f32
    float* out = (float*)d_out;                   // [16][20000] f32

    const size_t fragShorts = (size_t)PREP_TASKS * 8;                // 524288 u16
    const size_t needed     = fragShorts * sizeof(unsigned short);   // 1 MB

    if (ws_size >= needed) {
        unsigned short* Bf = (unsigned short*)d_ws;
        prep2_kernel<<<PREP_TASKS / 256, 256, 0, stream>>>(attn, vw, Bf);
        main_kernel<<<dim3(NB, NLT), 256, 0, stream>>>(Bf, sdelta, embt, out);
    } else {
        fallback_kernel<<<(NB * LMAX + 255) / 256, 256, 0, stream>>>(attn, sdelta, embt, vw, out);
    }
}